// Round 15
// baseline (143.259 us; speedup 1.0000x reference)
//
#include <hip/hip_runtime.h>
#include <hip/hip_bf16.h>

#define H_DIM 1024
#define NHEAD 16
#define HDIM  64
#define BATCH 2
#define SEQ   2048
#define MTOT  (BATCH*SEQ)   // 4096
#define LOG2E 1.4426950408889634f

typedef _Float16 f16x8 __attribute__((ext_vector_type(8)));
typedef float  f32x4  __attribute__((ext_vector_type(4)));
typedef float  f32x16 __attribute__((ext_vector_type(16)));
typedef short  short8 __attribute__((ext_vector_type(8)));
typedef unsigned uint2v __attribute__((ext_vector_type(2)));
typedef unsigned short u16;

static __device__ __forceinline__ u16 f2h(float f) {   // RNE fp32->fp16
  _Float16 h = (_Float16)f;
  return __builtin_bit_cast(u16, h);
}

// async global->LDS, 16B per lane. LDS dest = wave-uniform base + lane*16.
static __device__ __forceinline__ void load_lds16(const void* g, void* l) {
  __builtin_amdgcn_global_load_lds(
      (const __attribute__((address_space(1))) unsigned int*)g,
      (__attribute__((address_space(3))) unsigned int*)l, 16, 0, 0);
}

// ---------------------------------------------------------------------------
// All fp32->fp16 conversions in ONE dispatch.
// Wo is pre-scaled by 1/8 (exact) so the fused O-projection can use a
// fp16 reciprocal scaled by 8 (keeps it in fp16 normal range).
// ---------------------------------------------------------------------------
#define N8X (MTOT * H_DIM / 8)          // 524288
#define N8W (H_DIM * H_DIM / 8)         // 131072

__global__ __launch_bounds__(256) void conv_all(
    const float* __restrict__ x,  const float* __restrict__ Wq,
    const float* __restrict__ Wk, const float* __restrict__ Wv,
    const float* __restrict__ Wo,
    u16* __restrict__ xb, u16* __restrict__ W3, u16* __restrict__ Wo16) {
  int gi = blockIdx.x * 256 + threadIdx.x;
  const float* src;
  u16* dst;
  int ci;
  float scale = 1.0f;
  if (gi < N8X) {
    src = x; dst = xb; ci = gi;
  } else {
    int j = gi - N8X;
    int which = j >> 17;           // /131072
    ci = j & (N8W - 1);
    src = which == 0 ? Wq : (which == 1 ? Wk : (which == 2 ? Wv : Wo));
    dst = which < 3 ? W3 + (size_t)which * (N8W * 8) : Wo16;
    if (which == 3) scale = 0.125f;
  }
  float4 a = ((const float4*)src)[ci * 2];
  float4 b = ((const float4*)src)[ci * 2 + 1];
  union { u16 u[8]; short8 s; } r;
  r.u[0] = f2h(a.x * scale); r.u[1] = f2h(a.y * scale);
  r.u[2] = f2h(a.z * scale); r.u[3] = f2h(a.w * scale);
  r.u[4] = f2h(b.x * scale); r.u[5] = f2h(b.y * scale);
  r.u[6] = f2h(b.z * scale); r.u[7] = f2h(b.w * scale);
  *(short8*)&dst[ci * 8] = r.s;
}

// ---------------------------------------------------------------------------
// QKV fused GEMM (m97 structure), fp16 MFMA. M=4096, N=3072, K=1024.
// ---------------------------------------------------------------------------
#define BK 32

__global__ __launch_bounds__(256) void gemm_qkv(
    const u16* __restrict__ Xb, const u16* __restrict__ W3,
    const float* __restrict__ bq, const float* __restrict__ bk2,
    const float* __restrict__ bv,
    u16* __restrict__ qp, u16* __restrict__ kp, u16* __restrict__ vp) {
  __shared__ __align__(16) u16 Al[128 * BK];
  __shared__ __align__(16) u16 Bl[128 * BK];
  const int tid = threadIdx.x;
  const int w = tid >> 6, l = tid & 63, lg = l >> 4, lc = l & 15;
  const int wr = w >> 1, wc = w & 1;
  const int m0 = blockIdx.y * 128, n0 = blockIdx.x * 128;
  const int sr = w * 16 + (l >> 2);
  const int sc = (l & 3) * 8;

  f32x4 acc[4][4];
#pragma unroll
  for (int i = 0; i < 4; i++)
#pragma unroll
    for (int j = 0; j < 4; j++) acc[i][j] = (f32x4){0.f, 0.f, 0.f, 0.f};

  for (int k0 = 0; k0 < H_DIM; k0 += BK) {
    __syncthreads();
    load_lds16(&Xb[(size_t)(m0 + sr) * H_DIM + k0 + sc],      &Al[w * 512]);
    load_lds16(&Xb[(size_t)(m0 + 64 + sr) * H_DIM + k0 + sc], &Al[2048 + w * 512]);
    load_lds16(&W3[(size_t)(n0 + sr) * H_DIM + k0 + sc],      &Bl[w * 512]);
    load_lds16(&W3[(size_t)(n0 + 64 + sr) * H_DIM + k0 + sc], &Bl[2048 + w * 512]);
    __syncthreads();

    f16x8 af[4], bfr[4];
#pragma unroll
    for (int mi = 0; mi < 4; mi++)
      af[mi] = *(const f16x8*)&Al[(wr * 64 + mi * 16 + lc) * BK + lg * 8];
#pragma unroll
    for (int nj = 0; nj < 4; nj++)
      bfr[nj] = *(const f16x8*)&Bl[(wc * 64 + nj * 16 + lc) * BK + lg * 8];
#pragma unroll
    for (int mi = 0; mi < 4; mi++)
#pragma unroll
      for (int nj = 0; nj < 4; nj++)
        acc[mi][nj] = __builtin_amdgcn_mfma_f32_16x16x32_f16(af[mi], bfr[nj],
                                                             acc[mi][nj], 0, 0, 0);
  }

  const int np = n0 >> 10;
  u16* outp = np == 0 ? qp : (np == 1 ? kp : vp);
  const float* bias = np == 0 ? bq : (np == 1 ? bk2 : bv);
  const float scale = np == 0 ? (0.125f * LOG2E) : 1.0f;
  const int nc0 = (n0 & 1023) + wc * 64;
  float bvals[4];
#pragma unroll
  for (int nj = 0; nj < 4; nj++) bvals[nj] = bias[nc0 + nj * 16 + lc];
#pragma unroll
  for (int mi = 0; mi < 4; mi++)
#pragma unroll
    for (int nj = 0; nj < 4; nj++)
#pragma unroll
      for (int r = 0; r < 4; r++) {
        int row = m0 + wr * 64 + mi * 16 + lg * 4 + r;
        outp[(size_t)row * 1024 + nc0 + nj * 16 + lc] =
            f2h((acc[mi][nj][r] + bvals[nj]) * scale);
      }
}

// ---------------------------------------------------------------------------
// O-projection FUSED with KV-split combine:
//   A[m][k] = (O0[m][k] + O1[m][k]) * (8 / l(m, k>>6))   [fp16, reg-staged]
//   out = A @ (Wo/8)^T + bias                             [fp32 out]
// A staged via packed-fp16 ops into the same linear LDS slots gload_lds used;
// B (Wo16, pre-scaled 1/8) stays on global_load_lds.
// ---------------------------------------------------------------------------
__global__ __launch_bounds__(256) void gemm_oproj_fused(
    const u16* __restrict__ Op0, const u16* __restrict__ Op1,
    const float* __restrict__ lpart, const u16* __restrict__ B16,
    const float* __restrict__ bias, float* __restrict__ out) {
  __shared__ __align__(16) u16 Al[128 * BK];
  __shared__ __align__(16) u16 Bl[128 * BK];
  const int tid = threadIdx.x;
  const int w = tid >> 6, l = tid & 63, lg = l >> 4, lc = l & 15;
  const int wr = w >> 1, wc = w & 1;
  const int m0 = blockIdx.y * 128, n0 = blockIdx.x * 128;
  const int sr = w * 16 + (l >> 2);
  const int sc = (l & 3) * 8;

  f32x4 acc[4][4];
#pragma unroll
  for (int i = 0; i < 4; i++)
#pragma unroll
    for (int j = 0; j < 4; j++) acc[i][j] = (f32x4){0.f, 0.f, 0.f, 0.f};

  for (int head = 0; head < NHEAD; head++) {
    // per-head reciprocal for this thread's two staging rows (8/l: fp16-normal)
    float lt0 = lpart[(size_t)head * MTOT + m0 + sr] +
                lpart[((size_t)NHEAD + head) * MTOT + m0 + sr];
    float lt1 = lpart[(size_t)head * MTOT + m0 + 64 + sr] +
                lpart[((size_t)NHEAD + head) * MTOT + m0 + 64 + sr];
    _Float16 iv0 = (_Float16)(8.0f / lt0);
    _Float16 iv1 = (_Float16)(8.0f / lt1);
    f16x8 iv0v = {iv0, iv0, iv0, iv0, iv0, iv0, iv0, iv0};
    f16x8 iv1v = {iv1, iv1, iv1, iv1, iv1, iv1, iv1, iv1};
#pragma unroll
    for (int kk = 0; kk < 2; kk++) {
      const int k0 = head * 64 + kk * 32;
      __syncthreads();
      load_lds16(&B16[(size_t)(n0 + sr) * H_DIM + k0 + sc],      &Bl[w * 512]);
      load_lds16(&B16[(size_t)(n0 + 64 + sr) * H_DIM + k0 + sc], &Bl[2048 + w * 512]);
      // reg-staged A chunks (packed fp16 add+mul), same linear slots
      f16x8 a0 = *(const f16x8*)&Op0[(size_t)(m0 + sr) * H_DIM + k0 + sc];
      f16x8 a1 = *(const f16x8*)&Op1[(size_t)(m0 + sr) * H_DIM + k0 + sc];
      f16x8 c0 = (a0 + a1) * iv0v;
      f16x8 b0 = *(const f16x8*)&Op0[(size_t)(m0 + 64 + sr) * H_DIM + k0 + sc];
      f16x8 b1 = *(const f16x8*)&Op1[(size_t)(m0 + 64 + sr) * H_DIM + k0 + sc];
      f16x8 c1 = (b0 + b1) * iv1v;
      *(f16x8*)&Al[tid * 8] = c0;
      *(f16x8*)&Al[2048 + tid * 8] = c1;
      __syncthreads();

      f16x8 af[4], bfr[4];
#pragma unroll
      for (int mi = 0; mi < 4; mi++)
        af[mi] = *(const f16x8*)&Al[(wr * 64 + mi * 16 + lc) * BK + lg * 8];
#pragma unroll
      for (int nj = 0; nj < 4; nj++)
        bfr[nj] = *(const f16x8*)&Bl[(wc * 64 + nj * 16 + lc) * BK + lg * 8];
#pragma unroll
      for (int mi = 0; mi < 4; mi++)
#pragma unroll
        for (int nj = 0; nj < 4; nj++)
          acc[mi][nj] = __builtin_amdgcn_mfma_f32_16x16x32_f16(af[mi], bfr[nj],
                                                               acc[mi][nj], 0, 0, 0);
    }
  }

  const int nc0 = n0 + wc * 64;
  float bvals[4];
#pragma unroll
  for (int nj = 0; nj < 4; nj++) bvals[nj] = bias[nc0 + nj * 16 + lc];
#pragma unroll
  for (int mi = 0; mi < 4; mi++)
#pragma unroll
    for (int nj = 0; nj < 4; nj++)
#pragma unroll
      for (int r = 0; r < 4; r++) {
        int row = m0 + wr * 64 + mi * 16 + lg * 4 + r;
        out[(size_t)row * 1024 + nc0 + nj * 16 + lc] = acc[mi][nj][r] + bvals[nj];
      }
}

// ---------------------------------------------------------------------------
// Flash attention (r10 exact — best measured 64 us): 32 q/wave (32x32x16
// MFMA), P in-register via permlane32_swap, KV-split x2, no-max log2
// softmax, single-buffered Ks/Vt with chunk-XOR layouts.
// Block = 256 thr = 4 waves, 128 q-rows. KV tiles 64, KTILES=16.
// ---------------------------------------------------------------------------
#define KTILES 16

__global__ __launch_bounds__(256, 4) void attn_mfma7(
    const u16* __restrict__ q, const u16* __restrict__ k,
    const u16* __restrict__ v, u16* __restrict__ Opart,
    float* __restrict__ lpart) {
  __shared__ __align__(16) u16 Ks[64 * 64];
  __shared__ __align__(16) u16 Vt[64 * 64];

  const int tid = threadIdx.x;
  const int w = tid >> 6, l = tid & 63;
  const int l31 = l & 31, l5 = l >> 5;
  // XCD swizzle (bijective, 1024 wgs)
  const int wg = (blockIdx.x & 7) * 128 + (blockIdx.x >> 3);
  const int qt   = wg & 15;
  const int half = (wg >> 4) & 1;
  const int h    = (wg >> 5) & 15;
  const int b    = wg >> 9;
  const size_t row0 = (size_t)b * SEQ;
  const int grow = qt * 128 + w * 32 + l31;

  // Q B-frags: col=q=l31, k(d) = dc*16 + 8*l5 + j
  f16x8 qf[4];
  {
    const u16* qp = q + (row0 + grow) * H_DIM + h * HDIM + 8 * l5;
#pragma unroll
    for (int dc = 0; dc < 4; dc++)
      qf[dc] = *(const f16x8*)(qp + dc * 16);
  }

  // K staging: 2x global_load_lds per thread, pre-swizzled source.
  // Ks layout: (key,d) at key*64 + ((d>>3)^(key&7))*8 + (d&7)
  const int c1 = tid + 256;
  const u16* ksrc0 = k + (row0 + half * 1024 + (tid >> 3)) * H_DIM + h * HDIM
                       + ((tid & 7) ^ ((tid >> 3) & 7)) * 8;
  const u16* ksrc1 = k + (row0 + half * 1024 + (c1 >> 3)) * H_DIM + h * HDIM
                       + ((c1 & 7) ^ ((c1 >> 3) & 7)) * 8;

  // V staging: lane owns d = tid&63, key-octets ko, ko+4.
  // Vt layout: (d,key) at d*64 + ((key>>3)^(d&7))*8 + (key&7)
  const int vd = tid & 63, ko = tid >> 6;
  const u16* vsrc = v + (row0 + half * 1024 + ko * 8) * H_DIM + h * HDIM + vd;
  const int vwo0 = vd * 64 + ((ko)     ^ (vd & 7)) * 8;
  const int vwo1 = vd * 64 + ((ko + 4) ^ (vd & 7)) * 8;

  uint4 rV0, rV1;
  {
    unsigned a0 = vsrc[0 * H_DIM], a1 = vsrc[1 * H_DIM];
    unsigned a2 = vsrc[2 * H_DIM], a3 = vsrc[3 * H_DIM];
    unsigned a4 = vsrc[4 * H_DIM], a5 = vsrc[5 * H_DIM];
    unsigned a6 = vsrc[6 * H_DIM], a7 = vsrc[7 * H_DIM];
    rV0.x = a0 | (a1 << 16); rV0.y = a2 | (a3 << 16);
    rV0.z = a4 | (a5 << 16); rV0.w = a6 | (a7 << 16);
    const u16* v2 = vsrc + 32 * H_DIM;
    unsigned b0 = v2[0 * H_DIM], b1 = v2[1 * H_DIM];
    unsigned b2 = v2[2 * H_DIM], b3 = v2[3 * H_DIM];
    unsigned b4 = v2[4 * H_DIM], b5 = v2[5 * H_DIM];
    unsigned b6 = v2[6 * H_DIM], b7 = v2[7 * H_DIM];
    rV1.x = b0 | (b1 << 16); rV1.y = b2 | (b3 << 16);
    rV1.z = b4 | (b5 << 16); rV1.w = b6 | (b7 << 16);
  }

  f32x16 Oacc[2];
#pragma unroll
  for (int i = 0; i < 2; i++)
#pragma unroll
    for (int r = 0; r < 16; r++) Oacc[i][r] = 0.f;
  float lS = 0.f;

  for (int t = 0; t < KTILES; ++t) {
    __syncthreads();                       // prev tile reads done
    load_lds16(ksrc0, &Ks[w * 512]);
    load_lds16(ksrc1, &Ks[2048 + w * 512]);
    *(uint4*)&Vt[vwo0] = rV0;
    *(uint4*)&Vt[vwo1] = rV1;
    __syncthreads();                       // K+V visible
    ksrc0 += 64 * H_DIM;
    ksrc1 += 64 * H_DIM;

    if (t + 1 < KTILES) {                  // prefetch next V into regs
      vsrc += 64 * H_DIM;
      unsigned a0 = vsrc[0 * H_DIM], a1 = vsrc[1 * H_DIM];
      unsigned a2 = vsrc[2 * H_DIM], a3 = vsrc[3 * H_DIM];
      unsigned a4 = vsrc[4 * H_DIM], a5 = vsrc[5 * H_DIM];
      unsigned a6 = vsrc[6 * H_DIM], a7 = vsrc[7 * H_DIM];
      rV0.x = a0 | (a1 << 16); rV0.y = a2 | (a3 << 16);
      rV0.z = a4 | (a5 << 16); rV0.w = a6 | (a7 << 16);
      const u16* v2 = vsrc + 32 * H_DIM;
      unsigned b0 = v2[0 * H_DIM], b1 = v2[1 * H_DIM];
      unsigned b2 = v2[2 * H_DIM], b3 = v2[3 * H_DIM];
      unsigned b4 = v2[4 * H_DIM], b5 = v2[5 * H_DIM];
      unsigned b6 = v2[6 * H_DIM], b7 = v2[7 * H_DIM];
      rV1.x = b0 | (b1 << 16); rV1.y = b2 | (b3 << 16);
      rV1.z = b4 | (b5 << 16); rV1.w = b6 | (b7 << 16);
    }

    // ---- QK + exp + pack ----
    unsigned pw[2][4][2];
    float ps = 0.f;
#pragma unroll
    for (int kc = 0; kc < 2; kc++) {
      f32x16 s;
#pragma unroll
      for (int r = 0; r < 16; r++) s[r] = 0.f;
      const int key = kc * 32 + l31;
      const int rowb = key * 64, keyx = key & 7;
#pragma unroll
      for (int dc = 0; dc < 4; dc++) {
        f16x8 af = *(const f16x8*)&Ks[rowb + (((dc << 1) + l5) ^ keyx) * 8];
        s = __builtin_amdgcn_mfma_f32_32x32x16_f16(af, qf[dc], s, 0, 0, 0);
      }
#pragma unroll
      for (int rh = 0; rh < 4; rh++)
#pragma unroll
        for (int k1 = 0; k1 < 2; k1++) {
          float e0 = exp2f(s[4 * rh + 2 * k1]);
          float e1 = exp2f(s[4 * rh + 2 * k1 + 1]);
          ps += e0 + e1;
          pw[kc][rh][k1] = __builtin_bit_cast(
              unsigned, __builtin_amdgcn_cvt_pkrtz(e0, e1));
        }
    }
    lS += ps;

    // ---- PV: B-frags via permlane32_swap, A-frags from Vt ----
#pragma unroll
    for (int kcc = 0; kcc < 4; kcc++) {
      union { unsigned u[4]; f16x8 v8; } bf;
      const int kcs = kcc >> 1, rhA = (kcc & 1) << 1;
#pragma unroll
      for (int k1 = 0; k1 < 2; k1++) {
        uint2v xy = __builtin_amdgcn_permlane32_swap(
            pw[kcs][rhA][k1], pw[kcs][rhA + 1][k1], false, false);
        bf.u[k1] = xy.x;
        bf.u[2 + k1] = xy.y;
      }
#pragma unroll
      for (int dc2 = 0; dc2 < 2; dc2++) {
        const int d = dc2 * 32 + l31;
        f16x8 vf = *(const f16x8*)&Vt[d * 64 + (((kcc << 1) + l5) ^ (d & 7)) * 8];
        Oacc[dc2] = __builtin_amdgcn_mfma_f32_32x32x16_f16(vf, bf.v8,
                                                           Oacc[dc2], 0, 0, 0);
      }
    }
  }

  // ---- epilogue: store unnormalized fp16 O + per-half l ----
  lS += __shfl_xor(lS, 32);
  u16* ob = Opart + ((size_t)half * MTOT + row0 + grow) * H_DIM + h * HDIM;
#pragma unroll
  for (int dc2 = 0; dc2 < 2; dc2++)
#pragma unroll
    for (int rh = 0; rh < 4; rh++) {
      int d0 = dc2 * 32 + 8 * rh + 4 * l5;
      uint2 pd;
      pd.x = __builtin_bit_cast(unsigned, __builtin_amdgcn_cvt_pkrtz(
          Oacc[dc2][4 * rh + 0], Oacc[dc2][4 * rh + 1]));
      pd.y = __builtin_bit_cast(unsigned, __builtin_amdgcn_cvt_pkrtz(
          Oacc[dc2][4 * rh + 2], Oacc[dc2][4 * rh + 3]));
      *(uint2*)&ob[d0] = pd;
    }
  if (l < 32)
    lpart[((size_t)half * NHEAD + h) * MTOT + row0 + grow] = lS;
}

// ---------------------------------------------------------------------------
extern "C" void kernel_launch(void* const* d_in, const int* in_sizes, int n_in,
                              void* d_out, int out_size, void* d_ws, size_t ws_size,
                              hipStream_t stream) {
  const float* x  = (const float*)d_in[0];
  const float* Wq = (const float*)d_in[1];
  const float* bq = (const float*)d_in[2];
  const float* Wk = (const float*)d_in[3];
  const float* bk = (const float*)d_in[4];
  const float* Wv = (const float*)d_in[5];
  const float* bv = (const float*)d_in[6];
  const float* Wo = (const float*)d_in[7];
  const float* bo = (const float*)d_in[8];
  float* out = (float*)d_out;

  const size_t PL = (size_t)MTOT * H_DIM;   // 4M elems
  const size_t WN = (size_t)H_DIM * H_DIM;  // 1M elems
  u16* xb    = (u16*)d_ws;                  // fp16 planes
  u16* W3    = xb + PL;
  u16* qp    = W3 + 3 * WN;
  u16* kp    = qp + PL;
  u16* vp    = kp + PL;
  u16* Wo16  = vp + PL;                     // Wo / 8, fp16
  u16* Opart = Wo16 + WN;                   // [2][4096][1024] fp16
  float* lpart = (float*)(Opart + 2 * PL);  // [2][16][4096] fp32

  conv_all<<<(N8X + 4 * N8W) / 256, 256, 0, stream>>>(
      x, Wq, Wk, Wv, Wo, xb, W3, Wo16);

  gemm_qkv<<<dim3(3072 / 128, MTOT / 128), 256, 0, stream>>>(
      xb, W3, bq, bk, bv, qp, kp, vp);

  attn_mfma7<<<dim3(1024), 256, 0, stream>>>(qp, kp, vp, Opart, lpart);

  gemm_oproj_fused<<<dim3(1024 / 128, MTOT / 128), 256, 0, stream>>>(
      Opart, Opart + PL, lpart, Wo16, bo, out);
}

// Round 16
// 137.274 us; speedup vs baseline: 1.0436x; 1.0436x over previous
//
#include <hip/hip_runtime.h>
#include <hip/hip_bf16.h>

#define H_DIM 1024
#define NHEAD 16
#define HDIM  64
#define BATCH 2
#define SEQ   2048
#define MTOT  (BATCH*SEQ)   // 4096
#define LOG2E 1.4426950408889634f

typedef _Float16 f16x8 __attribute__((ext_vector_type(8)));
typedef float  f32x4  __attribute__((ext_vector_type(4)));
typedef float  f32x16 __attribute__((ext_vector_type(16)));
typedef short  short8 __attribute__((ext_vector_type(8)));
typedef unsigned uint2v __attribute__((ext_vector_type(2)));
typedef unsigned short u16;

static __device__ __forceinline__ u16 f2h(float f) {   // RNE fp32->fp16
  _Float16 h = (_Float16)f;
  return __builtin_bit_cast(u16, h);
}

// async global->LDS, 16B per lane. LDS dest = wave-uniform base + lane*16.
static __device__ __forceinline__ void load_lds16(const void* g, void* l) {
  __builtin_amdgcn_global_load_lds(
      (const __attribute__((address_space(1))) unsigned int*)g,
      (__attribute__((address_space(3))) unsigned int*)l, 16, 0, 0);
}

// ---------------------------------------------------------------------------
// All fp32->fp16 conversions in ONE dispatch.
// ---------------------------------------------------------------------------
#define N8X (MTOT * H_DIM / 8)          // 524288
#define N8W (H_DIM * H_DIM / 8)         // 131072

__global__ __launch_bounds__(256) void conv_all(
    const float* __restrict__ x,  const float* __restrict__ Wq,
    const float* __restrict__ Wk, const float* __restrict__ Wv,
    const float* __restrict__ Wo,
    u16* __restrict__ xb, u16* __restrict__ W3, u16* __restrict__ Wo16) {
  int gi = blockIdx.x * 256 + threadIdx.x;
  const float* src;
  u16* dst;
  int ci;
  if (gi < N8X) {
    src = x; dst = xb; ci = gi;
  } else {
    int j = gi - N8X;
    int which = j >> 17;           // /131072
    ci = j & (N8W - 1);
    src = which == 0 ? Wq : (which == 1 ? Wk : (which == 2 ? Wv : Wo));
    dst = which < 3 ? W3 + (size_t)which * (N8W * 8) : Wo16;
  }
  float4 a = ((const float4*)src)[ci * 2];
  float4 b = ((const float4*)src)[ci * 2 + 1];
  union { u16 u[8]; short8 s; } r;
  r.u[0] = f2h(a.x); r.u[1] = f2h(a.y); r.u[2] = f2h(a.z); r.u[3] = f2h(a.w);
  r.u[4] = f2h(b.x); r.u[5] = f2h(b.y); r.u[6] = f2h(b.z); r.u[7] = f2h(b.w);
  *(short8*)&dst[ci * 8] = r.s;
}

// ---------------------------------------------------------------------------
// QKV fused GEMM (m97 structure), fp16 MFMA. M=4096, N=3072, K=1024.
// ---------------------------------------------------------------------------
#define BK 32

__global__ __launch_bounds__(256) void gemm_qkv(
    const u16* __restrict__ Xb, const u16* __restrict__ W3,
    const float* __restrict__ bq, const float* __restrict__ bk2,
    const float* __restrict__ bv,
    u16* __restrict__ qp, u16* __restrict__ kp, u16* __restrict__ vp) {
  __shared__ __align__(16) u16 Al[128 * BK];
  __shared__ __align__(16) u16 Bl[128 * BK];
  const int tid = threadIdx.x;
  const int w = tid >> 6, l = tid & 63, lg = l >> 4, lc = l & 15;
  const int wr = w >> 1, wc = w & 1;
  const int m0 = blockIdx.y * 128, n0 = blockIdx.x * 128;
  const int sr = w * 16 + (l >> 2);
  const int sc = (l & 3) * 8;

  f32x4 acc[4][4];
#pragma unroll
  for (int i = 0; i < 4; i++)
#pragma unroll
    for (int j = 0; j < 4; j++) acc[i][j] = (f32x4){0.f, 0.f, 0.f, 0.f};

  for (int k0 = 0; k0 < H_DIM; k0 += BK) {
    __syncthreads();
    load_lds16(&Xb[(size_t)(m0 + sr) * H_DIM + k0 + sc],      &Al[w * 512]);
    load_lds16(&Xb[(size_t)(m0 + 64 + sr) * H_DIM + k0 + sc], &Al[2048 + w * 512]);
    load_lds16(&W3[(size_t)(n0 + sr) * H_DIM + k0 + sc],      &Bl[w * 512]);
    load_lds16(&W3[(size_t)(n0 + 64 + sr) * H_DIM + k0 + sc], &Bl[2048 + w * 512]);
    __syncthreads();

    f16x8 af[4], bfr[4];
#pragma unroll
    for (int mi = 0; mi < 4; mi++)
      af[mi] = *(const f16x8*)&Al[(wr * 64 + mi * 16 + lc) * BK + lg * 8];
#pragma unroll
    for (int nj = 0; nj < 4; nj++)
      bfr[nj] = *(const f16x8*)&Bl[(wc * 64 + nj * 16 + lc) * BK + lg * 8];
#pragma unroll
    for (int mi = 0; mi < 4; mi++)
#pragma unroll
      for (int nj = 0; nj < 4; nj++)
        acc[mi][nj] = __builtin_amdgcn_mfma_f32_16x16x32_f16(af[mi], bfr[nj],
                                                             acc[mi][nj], 0, 0, 0);
  }

  const int np = n0 >> 10;
  u16* outp = np == 0 ? qp : (np == 1 ? kp : vp);
  const float* bias = np == 0 ? bq : (np == 1 ? bk2 : bv);
  const float scale = np == 0 ? (0.125f * LOG2E) : 1.0f;
  const int nc0 = (n0 & 1023) + wc * 64;
  float bvals[4];
#pragma unroll
  for (int nj = 0; nj < 4; nj++) bvals[nj] = bias[nc0 + nj * 16 + lc];
#pragma unroll
  for (int mi = 0; mi < 4; mi++)
#pragma unroll
    for (int nj = 0; nj < 4; nj++)
#pragma unroll
      for (int r = 0; r < 4; r++) {
        int row = m0 + wr * 64 + mi * 16 + lg * 4 + r;
        outp[(size_t)row * 1024 + nc0 + nj * 16 + lc] =
            f2h((acc[mi][nj][r] + bvals[nj]) * scale);
      }
}

// ---------------------------------------------------------------------------
// O-projection, single-pass fp16: out = ctx @ Wo^T + bias, fp32 out.
// ---------------------------------------------------------------------------
__global__ __launch_bounds__(256) void gemm_oproj(
    const u16* __restrict__ A16, const u16* __restrict__ B16,
    const float* __restrict__ bias, float* __restrict__ out) {
  __shared__ __align__(16) u16 Al[128 * BK];
  __shared__ __align__(16) u16 Bl[128 * BK];
  const int tid = threadIdx.x;
  const int w = tid >> 6, l = tid & 63, lg = l >> 4, lc = l & 15;
  const int wr = w >> 1, wc = w & 1;
  const int m0 = blockIdx.y * 128, n0 = blockIdx.x * 128;
  const int sr = w * 16 + (l >> 2);
  const int sc = (l & 3) * 8;

  f32x4 acc[4][4];
#pragma unroll
  for (int i = 0; i < 4; i++)
#pragma unroll
    for (int j = 0; j < 4; j++) acc[i][j] = (f32x4){0.f, 0.f, 0.f, 0.f};

  for (int k0 = 0; k0 < H_DIM; k0 += BK) {
    __syncthreads();
    load_lds16(&A16[(size_t)(m0 + sr) * H_DIM + k0 + sc],      &Al[w * 512]);
    load_lds16(&A16[(size_t)(m0 + 64 + sr) * H_DIM + k0 + sc], &Al[2048 + w * 512]);
    load_lds16(&B16[(size_t)(n0 + sr) * H_DIM + k0 + sc],      &Bl[w * 512]);
    load_lds16(&B16[(size_t)(n0 + 64 + sr) * H_DIM + k0 + sc], &Bl[2048 + w * 512]);
    __syncthreads();

    f16x8 af[4], bfr[4];
#pragma unroll
    for (int mi = 0; mi < 4; mi++)
      af[mi] = *(const f16x8*)&Al[(wr * 64 + mi * 16 + lc) * BK + lg * 8];
#pragma unroll
    for (int nj = 0; nj < 4; nj++)
      bfr[nj] = *(const f16x8*)&Bl[(wc * 64 + nj * 16 + lc) * BK + lg * 8];
#pragma unroll
    for (int mi = 0; mi < 4; mi++)
#pragma unroll
      for (int nj = 0; nj < 4; nj++)
        acc[mi][nj] = __builtin_amdgcn_mfma_f32_16x16x32_f16(af[mi], bfr[nj],
                                                             acc[mi][nj], 0, 0, 0);
  }

  const int nc0 = n0 + wc * 64;
  float bvals[4];
#pragma unroll
  for (int nj = 0; nj < 4; nj++) bvals[nj] = bias[nc0 + nj * 16 + lc];
#pragma unroll
  for (int mi = 0; mi < 4; mi++)
#pragma unroll
    for (int nj = 0; nj < 4; nj++)
#pragma unroll
      for (int r = 0; r < 4; r++) {
        int row = m0 + wr * 64 + mi * 16 + lg * 4 + r;
        out[(size_t)row * 1024 + nc0 + nj * 16 + lc] = acc[mi][nj][r] + bvals[nj];
      }
}

// ---------------------------------------------------------------------------
// Flash attention (r10 exact — best measured 64 us): 32 q/wave (32x32x16
// MFMA), P in-register via permlane32_swap, KV-split x2, no-max log2
// softmax, single-buffered Ks/Vt with chunk-XOR layouts.
// Block = 256 thr = 4 waves, 128 q-rows. KV tiles 64, KTILES=16.
// ---------------------------------------------------------------------------
#define KTILES 16

__global__ __launch_bounds__(256, 4) void attn_mfma7(
    const u16* __restrict__ q, const u16* __restrict__ k,
    const u16* __restrict__ v, u16* __restrict__ Opart,
    float* __restrict__ lpart) {
  __shared__ __align__(16) u16 Ks[64 * 64];
  __shared__ __align__(16) u16 Vt[64 * 64];

  const int tid = threadIdx.x;
  const int w = tid >> 6, l = tid & 63;
  const int l31 = l & 31, l5 = l >> 5;
  // XCD swizzle (bijective, 1024 wgs)
  const int wg = (blockIdx.x & 7) * 128 + (blockIdx.x >> 3);
  const int qt   = wg & 15;
  const int half = (wg >> 4) & 1;
  const int h    = (wg >> 5) & 15;
  const int b    = wg >> 9;
  const size_t row0 = (size_t)b * SEQ;
  const int grow = qt * 128 + w * 32 + l31;

  // Q B-frags: col=q=l31, k(d) = dc*16 + 8*l5 + j
  f16x8 qf[4];
  {
    const u16* qp = q + (row0 + grow) * H_DIM + h * HDIM + 8 * l5;
#pragma unroll
    for (int dc = 0; dc < 4; dc++)
      qf[dc] = *(const f16x8*)(qp + dc * 16);
  }

  // K staging: 2x global_load_lds per thread, pre-swizzled source.
  // Ks layout: (key,d) at key*64 + ((d>>3)^(key&7))*8 + (d&7)
  const int c1 = tid + 256;
  const u16* ksrc0 = k + (row0 + half * 1024 + (tid >> 3)) * H_DIM + h * HDIM
                       + ((tid & 7) ^ ((tid >> 3) & 7)) * 8;
  const u16* ksrc1 = k + (row0 + half * 1024 + (c1 >> 3)) * H_DIM + h * HDIM
                       + ((c1 & 7) ^ ((c1 >> 3) & 7)) * 8;

  // V staging: lane owns d = tid&63, key-octets ko, ko+4.
  // Vt layout: (d,key) at d*64 + ((key>>3)^(d&7))*8 + (key&7)
  const int vd = tid & 63, ko = tid >> 6;
  const u16* vsrc = v + (row0 + half * 1024 + ko * 8) * H_DIM + h * HDIM + vd;
  const int vwo0 = vd * 64 + ((ko)     ^ (vd & 7)) * 8;
  const int vwo1 = vd * 64 + ((ko + 4) ^ (vd & 7)) * 8;

  uint4 rV0, rV1;
  {
    unsigned a0 = vsrc[0 * H_DIM], a1 = vsrc[1 * H_DIM];
    unsigned a2 = vsrc[2 * H_DIM], a3 = vsrc[3 * H_DIM];
    unsigned a4 = vsrc[4 * H_DIM], a5 = vsrc[5 * H_DIM];
    unsigned a6 = vsrc[6 * H_DIM], a7 = vsrc[7 * H_DIM];
    rV0.x = a0 | (a1 << 16); rV0.y = a2 | (a3 << 16);
    rV0.z = a4 | (a5 << 16); rV0.w = a6 | (a7 << 16);
    const u16* v2 = vsrc + 32 * H_DIM;
    unsigned b0 = v2[0 * H_DIM], b1 = v2[1 * H_DIM];
    unsigned b2 = v2[2 * H_DIM], b3 = v2[3 * H_DIM];
    unsigned b4 = v2[4 * H_DIM], b5 = v2[5 * H_DIM];
    unsigned b6 = v2[6 * H_DIM], b7 = v2[7 * H_DIM];
    rV1.x = b0 | (b1 << 16); rV1.y = b2 | (b3 << 16);
    rV1.z = b4 | (b5 << 16); rV1.w = b6 | (b7 << 16);
  }

  f32x16 Oacc[2];
#pragma unroll
  for (int i = 0; i < 2; i++)
#pragma unroll
    for (int r = 0; r < 16; r++) Oacc[i][r] = 0.f;
  float lS = 0.f;

  for (int t = 0; t < KTILES; ++t) {
    __syncthreads();                       // prev tile reads done
    load_lds16(ksrc0, &Ks[w * 512]);
    load_lds16(ksrc1, &Ks[2048 + w * 512]);
    *(uint4*)&Vt[vwo0] = rV0;
    *(uint4*)&Vt[vwo1] = rV1;
    __syncthreads();                       // K+V visible
    ksrc0 += 64 * H_DIM;
    ksrc1 += 64 * H_DIM;

    if (t + 1 < KTILES) {                  // prefetch next V into regs
      vsrc += 64 * H_DIM;
      unsigned a0 = vsrc[0 * H_DIM], a1 = vsrc[1 * H_DIM];
      unsigned a2 = vsrc[2 * H_DIM], a3 = vsrc[3 * H_DIM];
      unsigned a4 = vsrc[4 * H_DIM], a5 = vsrc[5 * H_DIM];
      unsigned a6 = vsrc[6 * H_DIM], a7 = vsrc[7 * H_DIM];
      rV0.x = a0 | (a1 << 16); rV0.y = a2 | (a3 << 16);
      rV0.z = a4 | (a5 << 16); rV0.w = a6 | (a7 << 16);
      const u16* v2 = vsrc + 32 * H_DIM;
      unsigned b0 = v2[0 * H_DIM], b1 = v2[1 * H_DIM];
      unsigned b2 = v2[2 * H_DIM], b3 = v2[3 * H_DIM];
      unsigned b4 = v2[4 * H_DIM], b5 = v2[5 * H_DIM];
      unsigned b6 = v2[6 * H_DIM], b7 = v2[7 * H_DIM];
      rV1.x = b0 | (b1 << 16); rV1.y = b2 | (b3 << 16);
      rV1.z = b4 | (b5 << 16); rV1.w = b6 | (b7 << 16);
    }

    // ---- QK + exp + pack ----
    unsigned pw[2][4][2];
    float ps = 0.f;
#pragma unroll
    for (int kc = 0; kc < 2; kc++) {
      f32x16 s;
#pragma unroll
      for (int r = 0; r < 16; r++) s[r] = 0.f;
      const int key = kc * 32 + l31;
      const int rowb = key * 64, keyx = key & 7;
#pragma unroll
      for (int dc = 0; dc < 4; dc++) {
        f16x8 af = *(const f16x8*)&Ks[rowb + (((dc << 1) + l5) ^ keyx) * 8];
        s = __builtin_amdgcn_mfma_f32_32x32x16_f16(af, qf[dc], s, 0, 0, 0);
      }
#pragma unroll
      for (int rh = 0; rh < 4; rh++)
#pragma unroll
        for (int k1 = 0; k1 < 2; k1++) {
          float e0 = exp2f(s[4 * rh + 2 * k1]);
          float e1 = exp2f(s[4 * rh + 2 * k1 + 1]);
          ps += e0 + e1;
          pw[kc][rh][k1] = __builtin_bit_cast(
              unsigned, __builtin_amdgcn_cvt_pkrtz(e0, e1));
        }
    }
    lS += ps;

    // ---- PV: B-frags via permlane32_swap, A-frags from Vt ----
#pragma unroll
    for (int kcc = 0; kcc < 4; kcc++) {
      union { unsigned u[4]; f16x8 v8; } bf;
      const int kcs = kcc >> 1, rhA = (kcc & 1) << 1;
#pragma unroll
      for (int k1 = 0; k1 < 2; k1++) {
        uint2v xy = __builtin_amdgcn_permlane32_swap(
            pw[kcs][rhA][k1], pw[kcs][rhA + 1][k1], false, false);
        bf.u[k1] = xy.x;
        bf.u[2 + k1] = xy.y;
      }
#pragma unroll
      for (int dc2 = 0; dc2 < 2; dc2++) {
        const int d = dc2 * 32 + l31;
        f16x8 vf = *(const f16x8*)&Vt[d * 64 + (((kcc << 1) + l5) ^ (d & 7)) * 8];
        Oacc[dc2] = __builtin_amdgcn_mfma_f32_32x32x16_f16(vf, bf.v8,
                                                           Oacc[dc2], 0, 0, 0);
      }
    }
  }

  // ---- epilogue: store unnormalized fp16 O + per-half l ----
  lS += __shfl_xor(lS, 32);
  u16* ob = Opart + ((size_t)half * MTOT + row0 + grow) * H_DIM + h * HDIM;
#pragma unroll
  for (int dc2 = 0; dc2 < 2; dc2++)
#pragma unroll
    for (int rh = 0; rh < 4; rh++) {
      int d0 = dc2 * 32 + 8 * rh + 4 * l5;
      uint2 pd;
      pd.x = __builtin_bit_cast(unsigned, __builtin_amdgcn_cvt_pkrtz(
          Oacc[dc2][4 * rh + 0], Oacc[dc2][4 * rh + 1]));
      pd.y = __builtin_bit_cast(unsigned, __builtin_amdgcn_cvt_pkrtz(
          Oacc[dc2][4 * rh + 2], Oacc[dc2][4 * rh + 3]));
      *(uint2*)&ob[d0] = pd;
    }
  if (l < 32)
    lpart[((size_t)half * NHEAD + h) * MTOT + row0 + grow] = lS;
}

// ---------------------------------------------------------------------------
// Combine: ctx = (O0 + O1) / (l0 + l1), fp16 in/out. 8 elems/thread.
// ---------------------------------------------------------------------------
__global__ __launch_bounds__(256) void combine_kernel(
    const u16* __restrict__ Opart, const float* __restrict__ lpart,
    u16* __restrict__ ctx) {
  int gi = blockIdx.x * 256 + threadIdx.x;   // 524288 total
  int r  = gi >> 7;                          // row 0..4095
  int d0 = (gi & 127) * 8;
  int hh = d0 >> 6;
  float lt = lpart[(size_t)hh * MTOT + r] + lpart[(size_t)(NHEAD + hh) * MTOT + r];
  float inv = 1.f / lt;
  short8 a = *(const short8*)&Opart[(size_t)r * H_DIM + d0];
  short8 c = *(const short8*)&Opart[(size_t)MTOT * H_DIM + (size_t)r * H_DIM + d0];
  union { u16 u[8]; short8 s; } rr;
#pragma unroll
  for (int j = 0; j < 8; j++) {
    float fa = (float)__builtin_bit_cast(_Float16, (u16)a[j]);
    float fc = (float)__builtin_bit_cast(_Float16, (u16)c[j]);
    rr.u[j] = f2h((fa + fc) * inv);
  }
  *(short8*)&ctx[(size_t)gi * 8] = rr.s;
}

// ---------------------------------------------------------------------------
extern "C" void kernel_launch(void* const* d_in, const int* in_sizes, int n_in,
                              void* d_out, int out_size, void* d_ws, size_t ws_size,
                              hipStream_t stream) {
  const float* x  = (const float*)d_in[0];
  const float* Wq = (const float*)d_in[1];
  const float* bq = (const float*)d_in[2];
  const float* Wk = (const float*)d_in[3];
  const float* bk = (const float*)d_in[4];
  const float* Wv = (const float*)d_in[5];
  const float* bv = (const float*)d_in[6];
  const float* Wo = (const float*)d_in[7];
  const float* bo = (const float*)d_in[8];
  float* out = (float*)d_out;

  const size_t PL = (size_t)MTOT * H_DIM;   // 4M elems
  const size_t WN = (size_t)H_DIM * H_DIM;  // 1M elems
  u16* xb    = (u16*)d_ws;                  // fp16 planes
  u16* W3    = xb + PL;
  u16* qp    = W3 + 3 * WN;
  u16* kp    = qp + PL;
  u16* vp    = kp + PL;
  u16* ctxp  = vp + PL;
  u16* Wo16  = ctxp + PL;
  u16* Opart = Wo16 + WN;                   // [2][4096][1024] fp16
  float* lpart = (float*)(Opart + 2 * PL);  // [2][16][4096] fp32

  conv_all<<<(N8X + 4 * N8W) / 256, 256, 0, stream>>>(
      x, Wq, Wk, Wv, Wo, xb, W3, Wo16);

  gemm_qkv<<<dim3(3072 / 128, MTOT / 128), 256, 0, stream>>>(
      xb, W3, bq, bk, bv, qp, kp, vp);

  attn_mfma7<<<dim3(1024), 256, 0, stream>>>(qp, kp, vp, Opart, lpart);

  combine_kernel<<<dim3((MTOT * H_DIM / 8) / 256), 256, 0, stream>>>(
      Opart, lpart, ctxp);

  gemm_oproj<<<dim3(1024 / 128, MTOT / 128), 256, 0, stream>>>(
      ctxp, Wo16, bo, out);
}

// Round 17
// 133.122 us; speedup vs baseline: 1.0761x; 1.0312x over previous
//
#include <hip/hip_runtime.h>
#include <hip/hip_bf16.h>

#define H_DIM 1024
#define NHEAD 16
#define HDIM  64
#define BATCH 2
#define SEQ   2048
#define MTOT  (BATCH*SEQ)   // 4096
#define LOG2E 1.4426950408889634f

typedef _Float16 f16x8 __attribute__((ext_vector_type(8)));
typedef float  f32x4  __attribute__((ext_vector_type(4)));
typedef float  f32x16 __attribute__((ext_vector_type(16)));
typedef short  short8 __attribute__((ext_vector_type(8)));
typedef unsigned uint2v __attribute__((ext_vector_type(2)));
typedef unsigned short u16;

static __device__ __forceinline__ u16 f2h(float f) {   // RNE fp32->fp16
  _Float16 h = (_Float16)f;
  return __builtin_bit_cast(u16, h);
}
static __device__ __forceinline__ float h2f(unsigned bits) {
  return (float)__builtin_bit_cast(_Float16, (u16)(bits & 0xffffu));
}

// async global->LDS, 16B per lane. LDS dest = wave-uniform base + lane*16.
static __device__ __forceinline__ void load_lds16(const void* g, void* l) {
  __builtin_amdgcn_global_load_lds(
      (const __attribute__((address_space(1))) unsigned int*)g,
      (__attribute__((address_space(3))) unsigned int*)l, 16, 0, 0);
}

// ---------------------------------------------------------------------------
// All fp32->fp16 conversions in ONE dispatch.
// ---------------------------------------------------------------------------
#define N8X (MTOT * H_DIM / 8)          // 524288
#define N8W (H_DIM * H_DIM / 8)         // 131072

__global__ __launch_bounds__(256) void conv_all(
    const float* __restrict__ x,  const float* __restrict__ Wq,
    const float* __restrict__ Wk, const float* __restrict__ Wv,
    const float* __restrict__ Wo,
    u16* __restrict__ xb, u16* __restrict__ W3, u16* __restrict__ Wo16) {
  int gi = blockIdx.x * 256 + threadIdx.x;
  const float* src;
  u16* dst;
  int ci;
  if (gi < N8X) {
    src = x; dst = xb; ci = gi;
  } else {
    int j = gi - N8X;
    int which = j >> 17;           // /131072
    ci = j & (N8W - 1);
    src = which == 0 ? Wq : (which == 1 ? Wk : (which == 2 ? Wv : Wo));
    dst = which < 3 ? W3 + (size_t)which * (N8W * 8) : Wo16;
  }
  float4 a = ((const float4*)src)[ci * 2];
  float4 b = ((const float4*)src)[ci * 2 + 1];
  union { u16 u[8]; short8 s; } r;
  r.u[0] = f2h(a.x); r.u[1] = f2h(a.y); r.u[2] = f2h(a.z); r.u[3] = f2h(a.w);
  r.u[4] = f2h(b.x); r.u[5] = f2h(b.y); r.u[6] = f2h(b.z); r.u[7] = f2h(b.w);
  *(short8*)&dst[ci * 8] = r.s;
}

// ---------------------------------------------------------------------------
// QKV fused GEMM (m97 structure), fp16 MFMA. M=4096, N=3072, K=1024.
// ---------------------------------------------------------------------------
#define BK 32

__global__ __launch_bounds__(256) void gemm_qkv(
    const u16* __restrict__ Xb, const u16* __restrict__ W3,
    const float* __restrict__ bq, const float* __restrict__ bk2,
    const float* __restrict__ bv,
    u16* __restrict__ qp, u16* __restrict__ kp, u16* __restrict__ vp) {
  __shared__ __align__(16) u16 Al[128 * BK];
  __shared__ __align__(16) u16 Bl[128 * BK];
  const int tid = threadIdx.x;
  const int w = tid >> 6, l = tid & 63, lg = l >> 4, lc = l & 15;
  const int wr = w >> 1, wc = w & 1;
  const int m0 = blockIdx.y * 128, n0 = blockIdx.x * 128;
  const int sr = w * 16 + (l >> 2);
  const int sc = (l & 3) * 8;

  f32x4 acc[4][4];
#pragma unroll
  for (int i = 0; i < 4; i++)
#pragma unroll
    for (int j = 0; j < 4; j++) acc[i][j] = (f32x4){0.f, 0.f, 0.f, 0.f};

  for (int k0 = 0; k0 < H_DIM; k0 += BK) {
    __syncthreads();
    load_lds16(&Xb[(size_t)(m0 + sr) * H_DIM + k0 + sc],      &Al[w * 512]);
    load_lds16(&Xb[(size_t)(m0 + 64 + sr) * H_DIM + k0 + sc], &Al[2048 + w * 512]);
    load_lds16(&W3[(size_t)(n0 + sr) * H_DIM + k0 + sc],      &Bl[w * 512]);
    load_lds16(&W3[(size_t)(n0 + 64 + sr) * H_DIM + k0 + sc], &Bl[2048 + w * 512]);
    __syncthreads();

    f16x8 af[4], bfr[4];
#pragma unroll
    for (int mi = 0; mi < 4; mi++)
      af[mi] = *(const f16x8*)&Al[(wr * 64 + mi * 16 + lc) * BK + lg * 8];
#pragma unroll
    for (int nj = 0; nj < 4; nj++)
      bfr[nj] = *(const f16x8*)&Bl[(wc * 64 + nj * 16 + lc) * BK + lg * 8];
#pragma unroll
    for (int mi = 0; mi < 4; mi++)
#pragma unroll
      for (int nj = 0; nj < 4; nj++)
        acc[mi][nj] = __builtin_amdgcn_mfma_f32_16x16x32_f16(af[mi], bfr[nj],
                                                             acc[mi][nj], 0, 0, 0);
  }

  const int np = n0 >> 10;
  u16* outp = np == 0 ? qp : (np == 1 ? kp : vp);
  const float* bias = np == 0 ? bq : (np == 1 ? bk2 : bv);
  const float scale = np == 0 ? (0.125f * LOG2E) : 1.0f;
  const int nc0 = (n0 & 1023) + wc * 64;
  float bvals[4];
#pragma unroll
  for (int nj = 0; nj < 4; nj++) bvals[nj] = bias[nc0 + nj * 16 + lc];
#pragma unroll
  for (int mi = 0; mi < 4; mi++)
#pragma unroll
    for (int nj = 0; nj < 4; nj++)
#pragma unroll
      for (int r = 0; r < 4; r++) {
        int row = m0 + wr * 64 + mi * 16 + lg * 4 + r;
        outp[(size_t)row * 1024 + nc0 + nj * 16 + lc] =
            f2h((acc[mi][nj][r] + bvals[nj]) * scale);
      }
}

// ---------------------------------------------------------------------------
// O-projection, single-pass fp16: out = ctx @ Wo^T + bias, fp32 out.
// ---------------------------------------------------------------------------
__global__ __launch_bounds__(256) void gemm_oproj(
    const u16* __restrict__ A16, const u16* __restrict__ B16,
    const float* __restrict__ bias, float* __restrict__ out) {
  __shared__ __align__(16) u16 Al[128 * BK];
  __shared__ __align__(16) u16 Bl[128 * BK];
  const int tid = threadIdx.x;
  const int w = tid >> 6, l = tid & 63, lg = l >> 4, lc = l & 15;
  const int wr = w >> 1, wc = w & 1;
  const int m0 = blockIdx.y * 128, n0 = blockIdx.x * 128;
  const int sr = w * 16 + (l >> 2);
  const int sc = (l & 3) * 8;

  f32x4 acc[4][4];
#pragma unroll
  for (int i = 0; i < 4; i++)
#pragma unroll
    for (int j = 0; j < 4; j++) acc[i][j] = (f32x4){0.f, 0.f, 0.f, 0.f};

  for (int k0 = 0; k0 < H_DIM; k0 += BK) {
    __syncthreads();
    load_lds16(&A16[(size_t)(m0 + sr) * H_DIM + k0 + sc],      &Al[w * 512]);
    load_lds16(&A16[(size_t)(m0 + 64 + sr) * H_DIM + k0 + sc], &Al[2048 + w * 512]);
    load_lds16(&B16[(size_t)(n0 + sr) * H_DIM + k0 + sc],      &Bl[w * 512]);
    load_lds16(&B16[(size_t)(n0 + 64 + sr) * H_DIM + k0 + sc], &Bl[2048 + w * 512]);
    __syncthreads();

    f16x8 af[4], bfr[4];
#pragma unroll
    for (int mi = 0; mi < 4; mi++)
      af[mi] = *(const f16x8*)&Al[(wr * 64 + mi * 16 + lc) * BK + lg * 8];
#pragma unroll
    for (int nj = 0; nj < 4; nj++)
      bfr[nj] = *(const f16x8*)&Bl[(wc * 64 + nj * 16 + lc) * BK + lg * 8];
#pragma unroll
    for (int mi = 0; mi < 4; mi++)
#pragma unroll
      for (int nj = 0; nj < 4; nj++)
        acc[mi][nj] = __builtin_amdgcn_mfma_f32_16x16x32_f16(af[mi], bfr[nj],
                                                             acc[mi][nj], 0, 0, 0);
  }

  const int nc0 = n0 + wc * 64;
  float bvals[4];
#pragma unroll
  for (int nj = 0; nj < 4; nj++) bvals[nj] = bias[nc0 + nj * 16 + lc];
#pragma unroll
  for (int mi = 0; mi < 4; mi++)
#pragma unroll
    for (int nj = 0; nj < 4; nj++)
#pragma unroll
      for (int r = 0; r < 4; r++) {
        int row = m0 + wr * 64 + mi * 16 + lg * 4 + r;
        out[(size_t)row * 1024 + nc0 + nj * 16 + lc] = acc[mi][nj][r] + bvals[nj];
      }
}

// ---------------------------------------------------------------------------
// Flash attention v11: r10 main loop x2 halves in ONE 512-thread block.
// Waves 0-3 process KV half 0, waves 4-7 half 1 (own Ks/Vt buffers, shared
// barriers). Epilogue: half-1 posts unnormalized fp16 O (chunk-XOR'd, 16KB,
// aliases Ks) + l (512B, aliases Vt) to LDS; half-0 combines, normalizes,
// writes fp16 ctx directly. Eliminates the combine kernel + Opart HBM trip.
// Grid 512 = 16qt x 16h x 2b -> 2 blocks/CU x 8 waves = 16 waves/CU (as r10).
// ---------------------------------------------------------------------------
#define KTILES 16

__global__ __launch_bounds__(512, 2) void attn_mfma11(
    const u16* __restrict__ q, const u16* __restrict__ k,
    const u16* __restrict__ v, u16* __restrict__ ctx) {
  __shared__ __align__(16) u16 Ks[2][64 * 64];   // 16KB (also ExO in epilogue)
  __shared__ __align__(16) u16 Vt[2][64 * 64];   // 16KB (also ExL in epilogue)

  const int tid = threadIdx.x;
  const int w8 = tid >> 6;            // 0..7
  const int half = w8 >> 2;           // KV half
  const int w = w8 & 3;               // wave within half
  const int l = tid & 63;
  const int l31 = l & 31, l5 = l >> 5;
  const int ht = tid & 255;           // thread within half
  // XCD swizzle (bijective, 512 wgs)
  const int wg = (blockIdx.x & 7) * 64 + (blockIdx.x >> 3);
  const int qt = wg & 15;
  const int h  = (wg >> 4) & 15;
  const int b  = wg >> 8;
  const size_t row0 = (size_t)b * SEQ;
  const int grow = qt * 128 + w * 32 + l31;

  // Q B-frags: col=q=l31, k(d) = dc*16 + 8*l5 + j  (same rows for both halves)
  f16x8 qf[4];
  {
    const u16* qp = q + (row0 + grow) * H_DIM + h * HDIM + 8 * l5;
#pragma unroll
    for (int dc = 0; dc < 4; dc++)
      qf[dc] = *(const f16x8*)(qp + dc * 16);
  }

  // K staging (per half): 2x global_load_lds per thread, pre-swizzled source.
  // Ks layout: (key,d) at key*64 + ((d>>3)^(key&7))*8 + (d&7)
  const int c1 = ht + 256;
  const u16* ksrc0 = k + (row0 + half * 1024 + (ht >> 3)) * H_DIM + h * HDIM
                       + ((ht & 7) ^ ((ht >> 3) & 7)) * 8;
  const u16* ksrc1 = k + (row0 + half * 1024 + (c1 >> 3)) * H_DIM + h * HDIM
                       + ((c1 & 7) ^ ((c1 >> 3) & 7)) * 8;

  // V staging (per half): lane owns d = ht&63, key-octets ko, ko+4.
  // Vt layout: (d,key) at d*64 + ((key>>3)^(d&7))*8 + (key&7)
  const int vd = ht & 63, ko = ht >> 6;
  const u16* vsrc = v + (row0 + half * 1024 + ko * 8) * H_DIM + h * HDIM + vd;
  const int vwo0 = vd * 64 + ((ko)     ^ (vd & 7)) * 8;
  const int vwo1 = vd * 64 + ((ko + 4) ^ (vd & 7)) * 8;

  uint4 rV0, rV1;
  {
    unsigned a0 = vsrc[0 * H_DIM], a1 = vsrc[1 * H_DIM];
    unsigned a2 = vsrc[2 * H_DIM], a3 = vsrc[3 * H_DIM];
    unsigned a4 = vsrc[4 * H_DIM], a5 = vsrc[5 * H_DIM];
    unsigned a6 = vsrc[6 * H_DIM], a7 = vsrc[7 * H_DIM];
    rV0.x = a0 | (a1 << 16); rV0.y = a2 | (a3 << 16);
    rV0.z = a4 | (a5 << 16); rV0.w = a6 | (a7 << 16);
    const u16* v2 = vsrc + 32 * H_DIM;
    unsigned b0 = v2[0 * H_DIM], b1 = v2[1 * H_DIM];
    unsigned b2 = v2[2 * H_DIM], b3 = v2[3 * H_DIM];
    unsigned b4 = v2[4 * H_DIM], b5 = v2[5 * H_DIM];
    unsigned b6 = v2[6 * H_DIM], b7 = v2[7 * H_DIM];
    rV1.x = b0 | (b1 << 16); rV1.y = b2 | (b3 << 16);
    rV1.z = b4 | (b5 << 16); rV1.w = b6 | (b7 << 16);
  }

  f32x16 Oacc[2];
#pragma unroll
  for (int i = 0; i < 2; i++)
#pragma unroll
    for (int r = 0; r < 16; r++) Oacc[i][r] = 0.f;
  float lS = 0.f;

  for (int t = 0; t < KTILES; ++t) {
    __syncthreads();                       // prev tile reads done (all waves)
    load_lds16(ksrc0, &Ks[half][w * 512]);
    load_lds16(ksrc1, &Ks[half][2048 + w * 512]);
    *(uint4*)&Vt[half][vwo0] = rV0;
    *(uint4*)&Vt[half][vwo1] = rV1;
    __syncthreads();                       // K+V visible
    ksrc0 += 64 * H_DIM;
    ksrc1 += 64 * H_DIM;

    if (t + 1 < KTILES) {                  // prefetch next V into regs
      vsrc += 64 * H_DIM;
      unsigned a0 = vsrc[0 * H_DIM], a1 = vsrc[1 * H_DIM];
      unsigned a2 = vsrc[2 * H_DIM], a3 = vsrc[3 * H_DIM];
      unsigned a4 = vsrc[4 * H_DIM], a5 = vsrc[5 * H_DIM];
      unsigned a6 = vsrc[6 * H_DIM], a7 = vsrc[7 * H_DIM];
      rV0.x = a0 | (a1 << 16); rV0.y = a2 | (a3 << 16);
      rV0.z = a4 | (a5 << 16); rV0.w = a6 | (a7 << 16);
      const u16* v2 = vsrc + 32 * H_DIM;
      unsigned b0 = v2[0 * H_DIM], b1 = v2[1 * H_DIM];
      unsigned b2 = v2[2 * H_DIM], b3 = v2[3 * H_DIM];
      unsigned b4 = v2[4 * H_DIM], b5 = v2[5 * H_DIM];
      unsigned b6 = v2[6 * H_DIM], b7 = v2[7 * H_DIM];
      rV1.x = b0 | (b1 << 16); rV1.y = b2 | (b3 << 16);
      rV1.z = b4 | (b5 << 16); rV1.w = b6 | (b7 << 16);
    }

    // ---- QK + exp + pack ----
    unsigned pw[2][4][2];
    float ps = 0.f;
#pragma unroll
    for (int kc = 0; kc < 2; kc++) {
      f32x16 s;
#pragma unroll
      for (int r = 0; r < 16; r++) s[r] = 0.f;
      const int key = kc * 32 + l31;
      const int rowb = key * 64, keyx = key & 7;
#pragma unroll
      for (int dc = 0; dc < 4; dc++) {
        f16x8 af = *(const f16x8*)&Ks[half][rowb + (((dc << 1) + l5) ^ keyx) * 8];
        s = __builtin_amdgcn_mfma_f32_32x32x16_f16(af, qf[dc], s, 0, 0, 0);
      }
#pragma unroll
      for (int rh = 0; rh < 4; rh++)
#pragma unroll
        for (int k1 = 0; k1 < 2; k1++) {
          float e0 = exp2f(s[4 * rh + 2 * k1]);
          float e1 = exp2f(s[4 * rh + 2 * k1 + 1]);
          ps += e0 + e1;
          pw[kc][rh][k1] = __builtin_bit_cast(
              unsigned, __builtin_amdgcn_cvt_pkrtz(e0, e1));
        }
    }
    lS += ps;

    // ---- PV: B-frags via permlane32_swap, A-frags from Vt ----
#pragma unroll
    for (int kcc = 0; kcc < 4; kcc++) {
      union { unsigned u[4]; f16x8 v8; } bf;
      const int kcs = kcc >> 1, rhA = (kcc & 1) << 1;
#pragma unroll
      for (int k1 = 0; k1 < 2; k1++) {
        uint2v xy = __builtin_amdgcn_permlane32_swap(
            pw[kcs][rhA][k1], pw[kcs][rhA + 1][k1], false, false);
        bf.u[k1] = xy.x;
        bf.u[2 + k1] = xy.y;
      }
#pragma unroll
      for (int dc2 = 0; dc2 < 2; dc2++) {
        const int d = dc2 * 32 + l31;
        f16x8 vf = *(const f16x8*)&Vt[half][d * 64 + (((kcc << 1) + l5) ^ (d & 7)) * 8];
        Oacc[dc2] = __builtin_amdgcn_mfma_f32_32x32x16_f16(vf, bf.v8,
                                                           Oacc[dc2], 0, 0, 0);
      }
    }
  }

  // ---- epilogue: in-block combine of the two halves ----
  __syncthreads();   // all tile reads done before Ks/Vt are reused
  lS += __shfl_xor(lS, 32);
  const int qloc = w * 32 + l31;          // 0..127, same for both halves
  u16* ExO = &Ks[0][0];                    // [128][64] fp16, chunk-XOR layout
  float* ExL = (float*)&Vt[0][0];          // [128] fp32

  if (half == 1) {
#pragma unroll
    for (int dc2 = 0; dc2 < 2; dc2++)
#pragma unroll
      for (int rh = 0; rh < 4; rh++) {
        uint2 pd;
        pd.x = __builtin_bit_cast(unsigned, __builtin_amdgcn_cvt_pkrtz(
            Oacc[dc2][4 * rh + 0], Oacc[dc2][4 * rh + 1]));
        pd.y = __builtin_bit_cast(unsigned, __builtin_amdgcn_cvt_pkrtz(
            Oacc[dc2][4 * rh + 2], Oacc[dc2][4 * rh + 3]));
        const int chunk = dc2 * 4 + rh;
        *(uint2*)&ExO[qloc * 64 + ((chunk ^ (qloc & 7)) << 3) + 4 * l5] = pd;
      }
    if (l < 32) ExL[qloc] = lS;
  }
  __syncthreads();
  if (half == 0) {
    float inv = 1.f / (lS + ExL[qloc]);
    const size_t obase = (row0 + grow) * H_DIM + h * HDIM;
#pragma unroll
    for (int dc2 = 0; dc2 < 2; dc2++)
#pragma unroll
      for (int rh = 0; rh < 4; rh++) {
        const int chunk = dc2 * 4 + rh;
        uint2 t = *(const uint2*)&ExO[qloc * 64 + ((chunk ^ (qloc & 7)) << 3) + 4 * l5];
        float o0 = (Oacc[dc2][4 * rh + 0] + h2f(t.x)) * inv;
        float o1 = (Oacc[dc2][4 * rh + 1] + h2f(t.x >> 16)) * inv;
        float o2 = (Oacc[dc2][4 * rh + 2] + h2f(t.y)) * inv;
        float o3 = (Oacc[dc2][4 * rh + 3] + h2f(t.y >> 16)) * inv;
        uint2 pd;
        pd.x = __builtin_bit_cast(unsigned, __builtin_amdgcn_cvt_pkrtz(o0, o1));
        pd.y = __builtin_bit_cast(unsigned, __builtin_amdgcn_cvt_pkrtz(o2, o3));
        *(uint2*)&ctx[obase + dc2 * 32 + 8 * rh + 4 * l5] = pd;
      }
  }
}

// ---------------------------------------------------------------------------
extern "C" void kernel_launch(void* const* d_in, const int* in_sizes, int n_in,
                              void* d_out, int out_size, void* d_ws, size_t ws_size,
                              hipStream_t stream) {
  const float* x  = (const float*)d_in[0];
  const float* Wq = (const float*)d_in[1];
  const float* bq = (const float*)d_in[2];
  const float* Wk = (const float*)d_in[3];
  const float* bk = (const float*)d_in[4];
  const float* Wv = (const float*)d_in[5];
  const float* bv = (const float*)d_in[6];
  const float* Wo = (const float*)d_in[7];
  const float* bo = (const float*)d_in[8];
  float* out = (float*)d_out;

  const size_t PL = (size_t)MTOT * H_DIM;   // 4M elems
  const size_t WN = (size_t)H_DIM * H_DIM;  // 1M elems
  u16* xb    = (u16*)d_ws;                  // fp16 planes
  u16* W3    = xb + PL;
  u16* qp    = W3 + 3 * WN;
  u16* kp    = qp + PL;
  u16* vp    = kp + PL;
  u16* ctxp  = vp + PL;
  u16* Wo16  = ctxp + PL;

  conv_all<<<(N8X + 4 * N8W) / 256, 256, 0, stream>>>(
      x, Wq, Wk, Wv, Wo, xb, W3, Wo16);

  gemm_qkv<<<dim3(3072 / 128, MTOT / 128), 256, 0, stream>>>(
      xb, W3, bq, bk, bv, qp, kp, vp);

  attn_mfma11<<<dim3(512), 512, 0, stream>>>(qp, kp, vp, ctxp);

  gemm_oproj<<<dim3(1024 / 128, MTOT / 128), 256, 0, stream>>>(
      ctxp, Wo16, bo, out);
}

// Round 18
// 128.808 us; speedup vs baseline: 1.1122x; 1.0335x over previous
//
#include <hip/hip_runtime.h>
#include <hip/hip_bf16.h>

#define H_DIM 1024
#define NHEAD 16
#define HDIM  64
#define BATCH 2
#define SEQ   2048
#define MTOT  (BATCH*SEQ)   // 4096
#define LOG2E 1.4426950408889634f

typedef _Float16 f16x8 __attribute__((ext_vector_type(8)));
typedef float  f32x4  __attribute__((ext_vector_type(4)));
typedef float  f32x16 __attribute__((ext_vector_type(16)));
typedef short  short8 __attribute__((ext_vector_type(8)));
typedef unsigned uint2v __attribute__((ext_vector_type(2)));
typedef unsigned short u16;

static __device__ __forceinline__ u16 f2h(float f) {   // RNE fp32->fp16
  _Float16 h = (_Float16)f;
  return __builtin_bit_cast(u16, h);
}
static __device__ __forceinline__ float h2f(unsigned bits) {
  return (float)__builtin_bit_cast(_Float16, (u16)(bits & 0xffffu));
}

// async global->LDS, 16B per lane. LDS dest = wave-uniform base + lane*16.
static __device__ __forceinline__ void load_lds16(const void* g, void* l) {
  __builtin_amdgcn_global_load_lds(
      (const __attribute__((address_space(1))) unsigned int*)g,
      (__attribute__((address_space(3))) unsigned int*)l, 16, 0, 0);
}

// ---------------------------------------------------------------------------
// All fp32->fp16 conversions in ONE dispatch.
// ---------------------------------------------------------------------------
#define N8X (MTOT * H_DIM / 8)          // 524288
#define N8W (H_DIM * H_DIM / 8)         // 131072

__global__ __launch_bounds__(256) void conv_all(
    const float* __restrict__ x,  const float* __restrict__ Wq,
    const float* __restrict__ Wk, const float* __restrict__ Wv,
    const float* __restrict__ Wo,
    u16* __restrict__ xb, u16* __restrict__ W3, u16* __restrict__ Wo16) {
  int gi = blockIdx.x * 256 + threadIdx.x;
  const float* src;
  u16* dst;
  int ci;
  if (gi < N8X) {
    src = x; dst = xb; ci = gi;
  } else {
    int j = gi - N8X;
    int which = j >> 17;           // /131072
    ci = j & (N8W - 1);
    src = which == 0 ? Wq : (which == 1 ? Wk : (which == 2 ? Wv : Wo));
    dst = which < 3 ? W3 + (size_t)which * (N8W * 8) : Wo16;
  }
  float4 a = ((const float4*)src)[ci * 2];
  float4 b = ((const float4*)src)[ci * 2 + 1];
  union { u16 u[8]; short8 s; } r;
  r.u[0] = f2h(a.x); r.u[1] = f2h(a.y); r.u[2] = f2h(a.z); r.u[3] = f2h(a.w);
  r.u[4] = f2h(b.x); r.u[5] = f2h(b.y); r.u[6] = f2h(b.z); r.u[7] = f2h(b.w);
  *(short8*)&dst[ci * 8] = r.s;
}

// ---------------------------------------------------------------------------
// QKV fused GEMM (m97 structure), fp16 MFMA. M=4096, N=3072, K=1024.
// ---------------------------------------------------------------------------
#define BK 32

__global__ __launch_bounds__(256) void gemm_qkv(
    const u16* __restrict__ Xb, const u16* __restrict__ W3,
    const float* __restrict__ bq, const float* __restrict__ bk2,
    const float* __restrict__ bv,
    u16* __restrict__ qp, u16* __restrict__ kp, u16* __restrict__ vp) {
  __shared__ __align__(16) u16 Al[128 * BK];
  __shared__ __align__(16) u16 Bl[128 * BK];
  const int tid = threadIdx.x;
  const int w = tid >> 6, l = tid & 63, lg = l >> 4, lc = l & 15;
  const int wr = w >> 1, wc = w & 1;
  const int m0 = blockIdx.y * 128, n0 = blockIdx.x * 128;
  const int sr = w * 16 + (l >> 2);
  const int sc = (l & 3) * 8;

  f32x4 acc[4][4];
#pragma unroll
  for (int i = 0; i < 4; i++)
#pragma unroll
    for (int j = 0; j < 4; j++) acc[i][j] = (f32x4){0.f, 0.f, 0.f, 0.f};

  for (int k0 = 0; k0 < H_DIM; k0 += BK) {
    __syncthreads();
    load_lds16(&Xb[(size_t)(m0 + sr) * H_DIM + k0 + sc],      &Al[w * 512]);
    load_lds16(&Xb[(size_t)(m0 + 64 + sr) * H_DIM + k0 + sc], &Al[2048 + w * 512]);
    load_lds16(&W3[(size_t)(n0 + sr) * H_DIM + k0 + sc],      &Bl[w * 512]);
    load_lds16(&W3[(size_t)(n0 + 64 + sr) * H_DIM + k0 + sc], &Bl[2048 + w * 512]);
    __syncthreads();

    f16x8 af[4], bfr[4];
#pragma unroll
    for (int mi = 0; mi < 4; mi++)
      af[mi] = *(const f16x8*)&Al[(wr * 64 + mi * 16 + lc) * BK + lg * 8];
#pragma unroll
    for (int nj = 0; nj < 4; nj++)
      bfr[nj] = *(const f16x8*)&Bl[(wc * 64 + nj * 16 + lc) * BK + lg * 8];
#pragma unroll
    for (int mi = 0; mi < 4; mi++)
#pragma unroll
      for (int nj = 0; nj < 4; nj++)
        acc[mi][nj] = __builtin_amdgcn_mfma_f32_16x16x32_f16(af[mi], bfr[nj],
                                                             acc[mi][nj], 0, 0, 0);
  }

  const int np = n0 >> 10;
  u16* outp = np == 0 ? qp : (np == 1 ? kp : vp);
  const float* bias = np == 0 ? bq : (np == 1 ? bk2 : bv);
  const float scale = np == 0 ? (0.125f * LOG2E) : 1.0f;
  const int nc0 = (n0 & 1023) + wc * 64;
  float bvals[4];
#pragma unroll
  for (int nj = 0; nj < 4; nj++) bvals[nj] = bias[nc0 + nj * 16 + lc];
#pragma unroll
  for (int mi = 0; mi < 4; mi++)
#pragma unroll
    for (int nj = 0; nj < 4; nj++)
#pragma unroll
      for (int r = 0; r < 4; r++) {
        int row = m0 + wr * 64 + mi * 16 + lg * 4 + r;
        outp[(size_t)row * 1024 + nc0 + nj * 16 + lc] =
            f2h((acc[mi][nj][r] + bvals[nj]) * scale);
      }
}

// ---------------------------------------------------------------------------
// O-projection, fp16: out = ctx @ Wo^T + bias, fp32 out.
// Retiled 128(M)x64(N) -> grid (16,32) = 512 blocks = 2 blocks/CU so the
// barrier/vmcnt drain of one block overlaps the other's compute (the 128x128
// version ran at exactly 1 block/CU and was drain-exposed, ~614 TF).
// 4 waves along M (32 rows each x 64 cols): 2x4 16x16 frags, 8 MFMA/K-step.
// ---------------------------------------------------------------------------
__global__ __launch_bounds__(256) void gemm_oproj(
    const u16* __restrict__ A16, const u16* __restrict__ B16,
    const float* __restrict__ bias, float* __restrict__ out) {
  __shared__ __align__(16) u16 Al[128 * BK];   // 8KB
  __shared__ __align__(16) u16 Bl[64 * BK];    // 4KB
  const int tid = threadIdx.x;
  const int w = tid >> 6, l = tid & 63, lg = l >> 4, lc = l & 15;
  const int m0 = blockIdx.y * 128, n0 = blockIdx.x * 64;
  // A staging rows: chunk c -> row c>>2, kcol (c&3)*8
  const int sra = tid >> 2, sca = (tid & 3) * 8;        // chunks 0..255
  const int srb = (tid >> 2) & 63;                      // B rows 0..63

  f32x4 acc[2][4];
#pragma unroll
  for (int i = 0; i < 2; i++)
#pragma unroll
    for (int j = 0; j < 4; j++) acc[i][j] = (f32x4){0.f, 0.f, 0.f, 0.f};

  for (int k0 = 0; k0 < H_DIM; k0 += BK) {
    __syncthreads();
    load_lds16(&A16[(size_t)(m0 + sra) * H_DIM + k0 + sca],      &Al[w * 512]);
    load_lds16(&A16[(size_t)(m0 + 64 + sra) * H_DIM + k0 + sca], &Al[2048 + w * 512]);
    load_lds16(&B16[(size_t)(n0 + srb) * H_DIM + k0 + sca],      &Bl[w * 512]);
    __syncthreads();

    f16x8 af[2], bfr[4];
#pragma unroll
    for (int mi = 0; mi < 2; mi++)
      af[mi] = *(const f16x8*)&Al[(w * 32 + mi * 16 + lc) * BK + lg * 8];
#pragma unroll
    for (int nj = 0; nj < 4; nj++)
      bfr[nj] = *(const f16x8*)&Bl[(nj * 16 + lc) * BK + lg * 8];
#pragma unroll
    for (int mi = 0; mi < 2; mi++)
#pragma unroll
      for (int nj = 0; nj < 4; nj++)
        acc[mi][nj] = __builtin_amdgcn_mfma_f32_16x16x32_f16(af[mi], bfr[nj],
                                                             acc[mi][nj], 0, 0, 0);
  }

  float bvals[4];
#pragma unroll
  for (int nj = 0; nj < 4; nj++) bvals[nj] = bias[n0 + nj * 16 + lc];
#pragma unroll
  for (int mi = 0; mi < 2; mi++)
#pragma unroll
    for (int nj = 0; nj < 4; nj++)
#pragma unroll
      for (int r = 0; r < 4; r++) {
        int row = m0 + w * 32 + mi * 16 + lg * 4 + r;
        out[(size_t)row * 1024 + n0 + nj * 16 + lc] = acc[mi][nj][r] + bvals[nj];
      }
}

// ---------------------------------------------------------------------------
// Flash attention v11 (r17, committed): r10 main loop x2 halves in ONE
// 512-thread block; in-block combine epilogue.
// ---------------------------------------------------------------------------
#define KTILES 16

__global__ __launch_bounds__(512, 2) void attn_mfma11(
    const u16* __restrict__ q, const u16* __restrict__ k,
    const u16* __restrict__ v, u16* __restrict__ ctx) {
  __shared__ __align__(16) u16 Ks[2][64 * 64];   // 16KB (also ExO in epilogue)
  __shared__ __align__(16) u16 Vt[2][64 * 64];   // 16KB (also ExL in epilogue)

  const int tid = threadIdx.x;
  const int w8 = tid >> 6;            // 0..7
  const int half = w8 >> 2;           // KV half
  const int w = w8 & 3;               // wave within half
  const int l = tid & 63;
  const int l31 = l & 31, l5 = l >> 5;
  const int ht = tid & 255;           // thread within half
  // XCD swizzle (bijective, 512 wgs)
  const int wg = (blockIdx.x & 7) * 64 + (blockIdx.x >> 3);
  const int qt = wg & 15;
  const int h  = (wg >> 4) & 15;
  const int b  = wg >> 8;
  const size_t row0 = (size_t)b * SEQ;
  const int grow = qt * 128 + w * 32 + l31;

  f16x8 qf[4];
  {
    const u16* qp = q + (row0 + grow) * H_DIM + h * HDIM + 8 * l5;
#pragma unroll
    for (int dc = 0; dc < 4; dc++)
      qf[dc] = *(const f16x8*)(qp + dc * 16);
  }

  const int c1 = ht + 256;
  const u16* ksrc0 = k + (row0 + half * 1024 + (ht >> 3)) * H_DIM + h * HDIM
                       + ((ht & 7) ^ ((ht >> 3) & 7)) * 8;
  const u16* ksrc1 = k + (row0 + half * 1024 + (c1 >> 3)) * H_DIM + h * HDIM
                       + ((c1 & 7) ^ ((c1 >> 3) & 7)) * 8;

  const int vd = ht & 63, ko = ht >> 6;
  const u16* vsrc = v + (row0 + half * 1024 + ko * 8) * H_DIM + h * HDIM + vd;
  const int vwo0 = vd * 64 + ((ko)     ^ (vd & 7)) * 8;
  const int vwo1 = vd * 64 + ((ko + 4) ^ (vd & 7)) * 8;

  uint4 rV0, rV1;
  {
    unsigned a0 = vsrc[0 * H_DIM], a1 = vsrc[1 * H_DIM];
    unsigned a2 = vsrc[2 * H_DIM], a3 = vsrc[3 * H_DIM];
    unsigned a4 = vsrc[4 * H_DIM], a5 = vsrc[5 * H_DIM];
    unsigned a6 = vsrc[6 * H_DIM], a7 = vsrc[7 * H_DIM];
    rV0.x = a0 | (a1 << 16); rV0.y = a2 | (a3 << 16);
    rV0.z = a4 | (a5 << 16); rV0.w = a6 | (a7 << 16);
    const u16* v2 = vsrc + 32 * H_DIM;
    unsigned b0 = v2[0 * H_DIM], b1 = v2[1 * H_DIM];
    unsigned b2 = v2[2 * H_DIM], b3 = v2[3 * H_DIM];
    unsigned b4 = v2[4 * H_DIM], b5 = v2[5 * H_DIM];
    unsigned b6 = v2[6 * H_DIM], b7 = v2[7 * H_DIM];
    rV1.x = b0 | (b1 << 16); rV1.y = b2 | (b3 << 16);
    rV1.z = b4 | (b5 << 16); rV1.w = b6 | (b7 << 16);
  }

  f32x16 Oacc[2];
#pragma unroll
  for (int i = 0; i < 2; i++)
#pragma unroll
    for (int r = 0; r < 16; r++) Oacc[i][r] = 0.f;
  float lS = 0.f;

  for (int t = 0; t < KTILES; ++t) {
    __syncthreads();
    load_lds16(ksrc0, &Ks[half][w * 512]);
    load_lds16(ksrc1, &Ks[half][2048 + w * 512]);
    *(uint4*)&Vt[half][vwo0] = rV0;
    *(uint4*)&Vt[half][vwo1] = rV1;
    __syncthreads();
    ksrc0 += 64 * H_DIM;
    ksrc1 += 64 * H_DIM;

    if (t + 1 < KTILES) {
      vsrc += 64 * H_DIM;
      unsigned a0 = vsrc[0 * H_DIM], a1 = vsrc[1 * H_DIM];
      unsigned a2 = vsrc[2 * H_DIM], a3 = vsrc[3 * H_DIM];
      unsigned a4 = vsrc[4 * H_DIM], a5 = vsrc[5 * H_DIM];
      unsigned a6 = vsrc[6 * H_DIM], a7 = vsrc[7 * H_DIM];
      rV0.x = a0 | (a1 << 16); rV0.y = a2 | (a3 << 16);
      rV0.z = a4 | (a5 << 16); rV0.w = a6 | (a7 << 16);
      const u16* v2 = vsrc + 32 * H_DIM;
      unsigned b0 = v2[0 * H_DIM], b1 = v2[1 * H_DIM];
      unsigned b2 = v2[2 * H_DIM], b3 = v2[3 * H_DIM];
      unsigned b4 = v2[4 * H_DIM], b5 = v2[5 * H_DIM];
      unsigned b6 = v2[6 * H_DIM], b7 = v2[7 * H_DIM];
      rV1.x = b0 | (b1 << 16); rV1.y = b2 | (b3 << 16);
      rV1.z = b4 | (b5 << 16); rV1.w = b6 | (b7 << 16);
    }

    unsigned pw[2][4][2];
    float ps = 0.f;
#pragma unroll
    for (int kc = 0; kc < 2; kc++) {
      f32x16 s;
#pragma unroll
      for (int r = 0; r < 16; r++) s[r] = 0.f;
      const int key = kc * 32 + l31;
      const int rowb = key * 64, keyx = key & 7;
#pragma unroll
      for (int dc = 0; dc < 4; dc++) {
        f16x8 af = *(const f16x8*)&Ks[half][rowb + (((dc << 1) + l5) ^ keyx) * 8];
        s = __builtin_amdgcn_mfma_f32_32x32x16_f16(af, qf[dc], s, 0, 0, 0);
      }
#pragma unroll
      for (int rh = 0; rh < 4; rh++)
#pragma unroll
        for (int k1 = 0; k1 < 2; k1++) {
          float e0 = exp2f(s[4 * rh + 2 * k1]);
          float e1 = exp2f(s[4 * rh + 2 * k1 + 1]);
          ps += e0 + e1;
          pw[kc][rh][k1] = __builtin_bit_cast(
              unsigned, __builtin_amdgcn_cvt_pkrtz(e0, e1));
        }
    }
    lS += ps;

#pragma unroll
    for (int kcc = 0; kcc < 4; kcc++) {
      union { unsigned u[4]; f16x8 v8; } bf;
      const int kcs = kcc >> 1, rhA = (kcc & 1) << 1;
#pragma unroll
      for (int k1 = 0; k1 < 2; k1++) {
        uint2v xy = __builtin_amdgcn_permlane32_swap(
            pw[kcs][rhA][k1], pw[kcs][rhA + 1][k1], false, false);
        bf.u[k1] = xy.x;
        bf.u[2 + k1] = xy.y;
      }
#pragma unroll
      for (int dc2 = 0; dc2 < 2; dc2++) {
        const int d = dc2 * 32 + l31;
        f16x8 vf = *(const f16x8*)&Vt[half][d * 64 + (((kcc << 1) + l5) ^ (d & 7)) * 8];
        Oacc[dc2] = __builtin_amdgcn_mfma_f32_32x32x16_f16(vf, bf.v8,
                                                           Oacc[dc2], 0, 0, 0);
      }
    }
  }

  // ---- epilogue: in-block combine of the two halves ----
  __syncthreads();
  lS += __shfl_xor(lS, 32);
  const int qloc = w * 32 + l31;
  u16* ExO = &Ks[0][0];
  float* ExL = (float*)&Vt[0][0];

  if (half == 1) {
#pragma unroll
    for (int dc2 = 0; dc2 < 2; dc2++)
#pragma unroll
      for (int rh = 0; rh < 4; rh++) {
        uint2 pd;
        pd.x = __builtin_bit_cast(unsigned, __builtin_amdgcn_cvt_pkrtz(
            Oacc[dc2][4 * rh + 0], Oacc[dc2][4 * rh + 1]));
        pd.y = __builtin_bit_cast(unsigned, __builtin_amdgcn_cvt_pkrtz(
            Oacc[dc2][4 * rh + 2], Oacc[dc2][4 * rh + 3]));
        const int chunk = dc2 * 4 + rh;
        *(uint2*)&ExO[qloc * 64 + ((chunk ^ (qloc & 7)) << 3) + 4 * l5] = pd;
      }
    if (l < 32) ExL[qloc] = lS;
  }
  __syncthreads();
  if (half == 0) {
    float inv = 1.f / (lS + ExL[qloc]);
    const size_t obase = (row0 + grow) * H_DIM + h * HDIM;
#pragma unroll
    for (int dc2 = 0; dc2 < 2; dc2++)
#pragma unroll
      for (int rh = 0; rh < 4; rh++) {
        const int chunk = dc2 * 4 + rh;
        uint2 t = *(const uint2*)&ExO[qloc * 64 + ((chunk ^ (qloc & 7)) << 3) + 4 * l5];
        float o0 = (Oacc[dc2][4 * rh + 0] + h2f(t.x)) * inv;
        float o1 = (Oacc[dc2][4 * rh + 1] + h2f(t.x >> 16)) * inv;
        float o2 = (Oacc[dc2][4 * rh + 2] + h2f(t.y)) * inv;
        float o3 = (Oacc[dc2][4 * rh + 3] + h2f(t.y >> 16)) * inv;
        uint2 pd;
        pd.x = __builtin_bit_cast(unsigned, __builtin_amdgcn_cvt_pkrtz(o0, o1));
        pd.y = __builtin_bit_cast(unsigned, __builtin_amdgcn_cvt_pkrtz(o2, o3));
        *(uint2*)&ctx[obase + dc2 * 32 + 8 * rh + 4 * l5] = pd;
      }
  }
}

// ---------------------------------------------------------------------------
extern "C" void kernel_launch(void* const* d_in, const int* in_sizes, int n_in,
                              void* d_out, int out_size, void* d_ws, size_t ws_size,
                              hipStream_t stream) {
  const float* x  = (const float*)d_in[0];
  const float* Wq = (const float*)d_in[1];
  const float* bq = (const float*)d_in[2];
  const float* Wk = (const float*)d_in[3];
  const float* bk = (const float*)d_in[4];
  const float* Wv = (const float*)d_in[5];
  const float* bv = (const float*)d_in[6];
  const float* Wo = (const float*)d_in[7];
  const float* bo = (const float*)d_in[8];
  float* out = (float*)d_out;

  const size_t PL = (size_t)MTOT * H_DIM;   // 4M elems
  const size_t WN = (size_t)H_DIM * H_DIM;  // 1M elems
  u16* xb    = (u16*)d_ws;                  // fp16 planes
  u16* W3    = xb + PL;
  u16* qp    = W3 + 3 * WN;
  u16* kp    = qp + PL;
  u16* vp    = kp + PL;
  u16* ctxp  = vp + PL;
  u16* Wo16  = ctxp + PL;

  conv_all<<<(N8X + 4 * N8W) / 256, 256, 0, stream>>>(
      x, Wq, Wk, Wv, Wo, xb, W3, Wo16);

  gemm_qkv<<<dim3(3072 / 128, MTOT / 128), 256, 0, stream>>>(
      xb, W3, bq, bk, bv, qp, kp, vp);

  attn_mfma11<<<dim3(512), 512, 0, stream>>>(qp, kp, vp, ctxp);

  gemm_oproj<<<dim3(1024 / 64, MTOT / 128), 256, 0, stream>>>(
      ctxp, Wo16, bo, out);
}